// Round 6
// baseline (298.343 us; speedup 1.0000x reference)
//
#include <hip/hip_runtime.h>

#define S_LEN 8192
#define C_CTX 21
#define E_DIM 128
#define G_DIM 36
#define H_DIM 1024
#define T_TAG 32
#define D_RAW 3444          // 21*(128+36)
#define DP 3456             // padded to multiple of 32 (108 K-iters)
#define START_TAG 30
#define STOP_TAG 31
#define NEGV -10000.0f
#define K_CHUNKS 256
#define L_CHUNK 32          // K_CHUNKS * L_CHUNK == S_LEN

typedef __bf16 bf16_t;
typedef __bf16 bf16x4 __attribute__((ext_vector_type(4)));
typedef __bf16 bf16x8 __attribute__((ext_vector_type(8)));
typedef float  f32x4  __attribute__((ext_vector_type(4)));

__device__ inline void async_copy16(const bf16_t* g, bf16_t* l) {
    __builtin_amdgcn_global_load_lds(
        (const __attribute__((address_space(1))) void*)g,
        (__attribute__((address_space(3))) void*)l, 16, 0, 0);
}

// ---------------- Phase 0: materialize padded bf16 X and W1 (one launch) ---
__global__ void build_all(const int* __restrict__ ctx, const float* __restrict__ gz,
                          const float* __restrict__ emb, const float* __restrict__ w1,
                          bf16_t* __restrict__ X, bf16_t* __restrict__ W) {
    const int b = blockIdx.x;
    if (b < S_LEN) {
        const int s = b;
        for (int g = threadIdx.x; g < DP / 4; g += 256) {   // 864 groups
            float4 v = {0.f, 0.f, 0.f, 0.f};
            if (g < D_RAW / 4) {                             // 861 real groups
                const int c  = g / 41;
                const int rg = g - c * 41;                   // 0..40
                if (rg < 32) v = *(const float4*)&emb[(size_t)ctx[s * C_CTX + c] * E_DIM + rg * 4];
                else         v = *(const float4*)&gz[((size_t)s * C_CTX + c) * G_DIM + (rg - 32) * 4];
            }
            bf16x4 o = {(bf16_t)v.x, (bf16_t)v.y, (bf16_t)v.z, (bf16_t)v.w};
            *(bf16x4*)&X[(size_t)s * DP + g * 4] = o;
        }
    } else {
        const int h = b - S_LEN;
        for (int g = threadIdx.x; g < DP / 4; g += 256) {
            float4 v = {0.f, 0.f, 0.f, 0.f};
            if (g < D_RAW / 4) v = *(const float4*)&w1[(size_t)h * D_RAW + g * 4];
            bf16x4 o = {(bf16_t)v.x, (bf16_t)v.y, (bf16_t)v.z, (bf16_t)v.w};
            *(bf16x4*)&W[(size_t)h * DP + g * 4] = o;
        }
    }
}

// ---------------- Phase 1: h = relu(X @ W1^T + b1), bf16 MFMA -------------
// 128x128 tile. LDS k-group swizzle kg^((row>>1)&3): conflict-free ds_read_b128.
__global__ __launch_bounds__(256) void gemm1(const bf16_t* __restrict__ X,
                                             const bf16_t* __restrict__ W,
                                             const float* __restrict__ b1,
                                             bf16_t* __restrict__ Hout) {
    __shared__ bf16_t As[128 * 32];
    __shared__ bf16_t Bs[128 * 32];
    const int tid  = threadIdx.x;
    const int wave = tid >> 6, lane = tid & 63;
    const int s0 = blockIdx.x * 128, h0 = blockIdx.y * 128;
    const int wm = (wave & 1) * 64, wn = (wave >> 1) * 64;

    const int rowA = tid >> 2;
    const int kgs  = (tid & 3) ^ ((rowA >> 1) & 3);   // swizzled source k-group
    const int colA = kgs * 8;
    const bf16_t* gA0 = X + (size_t)(s0 + rowA) * DP + colA;
    const bf16_t* gA1 = X + (size_t)(s0 + rowA + 64) * DP + colA;
    const bf16_t* gB0 = W + (size_t)(h0 + rowA) * DP + colA;
    const bf16_t* gB1 = W + (size_t)(h0 + rowA + 64) * DP + colA;
    bf16_t* lA0 = &As[tid * 8];
    bf16_t* lA1 = &As[(tid + 256) * 8];
    bf16_t* lB0 = &Bs[tid * 8];
    bf16_t* lB1 = &Bs[(tid + 256) * 8];

    const int lrow = lane & 15;
    const int kq   = ((lane >> 4) ^ ((lrow >> 1) & 3)) * 8;   // swizzled read offset

    f32x4 acc[4][4] = {};
    for (int k0 = 0; k0 < DP; k0 += 32) {
        async_copy16(gA0 + k0, lA0);
        async_copy16(gA1 + k0, lA1);
        async_copy16(gB0 + k0, lB0);
        async_copy16(gB1 + k0, lB1);
        __syncthreads();
        bf16x8 a[4], b[4];
#pragma unroll
        for (int mt = 0; mt < 4; ++mt)
            a[mt] = *(const bf16x8*)&As[(wm + mt * 16 + lrow) * 32 + kq];
#pragma unroll
        for (int nt = 0; nt < 4; ++nt)
            b[nt] = *(const bf16x8*)&Bs[(wn + nt * 16 + lrow) * 32 + kq];
#pragma unroll
        for (int mt = 0; mt < 4; ++mt)
#pragma unroll
            for (int nt = 0; nt < 4; ++nt)
                acc[mt][nt] = __builtin_amdgcn_mfma_f32_16x16x32_bf16(a[mt], b[nt], acc[mt][nt], 0, 0, 0);
        __syncthreads();
    }
    const int crow = (lane >> 4) * 4;
    const int ccol = lane & 15;
#pragma unroll
    for (int nt = 0; nt < 4; ++nt) {
        const int j = h0 + wn + nt * 16 + ccol;
        const float bv = b1[j];
#pragma unroll
        for (int mt = 0; mt < 4; ++mt) {
#pragma unroll
            for (int r = 0; r < 4; ++r) {
                const int s = s0 + wm + mt * 16 + crow + r;
                const float v = acc[mt][nt][r] + bv;
                Hout[(size_t)s * H_DIM + j] = (bf16_t)fmaxf(v, 0.f);
            }
        }
    }
}

// ---------------- Phase 2: feats = H @ w2^T + b2 (fp32 out), MFMA ----------
__global__ __launch_bounds__(256) void feats_mfma(const bf16_t* __restrict__ Hb,
                                                  const float* __restrict__ w2,
                                                  const float* __restrict__ b2,
                                                  float* __restrict__ F) {
    __shared__ bf16_t As[128 * 64];
    __shared__ bf16_t Bs[32 * 64];
    const int tid  = threadIdx.x;
    const int wave = tid >> 6, lane = tid & 63;
    const int s0 = blockIdx.x * 128;
    const int wm = wave * 32;

    const int arow = tid >> 3;
    const int akgs = (tid & 7) ^ (arow & 7);
    const bf16_t* gA = Hb + (size_t)(s0 + arow) * H_DIM + akgs * 8;
    const int brow = tid >> 3;
    const int bkgs = (tid & 7) ^ (brow & 7);
    const float* wp = w2 + (size_t)brow * H_DIM + bkgs * 8;
    bf16_t* lB = &Bs[tid * 8];

    const int lrow = lane & 15;

    f32x4 acc[2][2] = {};
    for (int k0 = 0; k0 < H_DIM; k0 += 64) {
#pragma unroll
        for (int i = 0; i < 4; ++i)
            async_copy16(gA + (size_t)i * 32 * H_DIM + k0, &As[(tid + i * 256) * 8]);
        const float4 x0 = *(const float4*)(wp + k0);
        const float4 x1 = *(const float4*)(wp + k0 + 4);
        bf16x8 bb = {(bf16_t)x0.x, (bf16_t)x0.y, (bf16_t)x0.z, (bf16_t)x0.w,
                     (bf16_t)x1.x, (bf16_t)x1.y, (bf16_t)x1.z, (bf16_t)x1.w};
        *(bf16x8*)lB = bb;
        __syncthreads();
#pragma unroll
        for (int ks = 0; ks < 2; ++ks) {
            const int kq = ((ks * 4 + (lane >> 4)) ^ (lrow & 7)) * 8;
            bf16x8 a[2], b[2];
#pragma unroll
            for (int mt = 0; mt < 2; ++mt)
                a[mt] = *(const bf16x8*)&As[(wm + mt * 16 + lrow) * 64 + kq];
#pragma unroll
            for (int nt = 0; nt < 2; ++nt)
                b[nt] = *(const bf16x8*)&Bs[(nt * 16 + lrow) * 64 + kq];
#pragma unroll
            for (int mt = 0; mt < 2; ++mt)
#pragma unroll
                for (int nt = 0; nt < 2; ++nt)
                    acc[mt][nt] = __builtin_amdgcn_mfma_f32_16x16x32_bf16(a[mt], b[nt], acc[mt][nt], 0, 0, 0);
        }
        __syncthreads();
    }
    const int crow = (lane >> 4) * 4;
    const int ccol = lane & 15;
#pragma unroll
    for (int nt = 0; nt < 2; ++nt) {
        const int j = nt * 16 + ccol;
        const float bv = b2[j];
#pragma unroll
        for (int mt = 0; mt < 2; ++mt) {
#pragma unroll
            for (int r = 0; r < 4; ++r) {
                const int s = s0 + wm + mt * 16 + crow + r;
                F[(size_t)s * T_TAG + j] = acc[mt][nt][r] + bv;
            }
        }
    }
}

// ---------------- CRF pass A: per-chunk matrix-chain products --------------
// 256 chunks of 32 steps: 1024 blocks (4/CU), chain length 31.
__global__ __launch_bounds__(256) void crfA(const float* __restrict__ F,
                                            const float* __restrict__ trans,
                                            float* __restrict__ QT,
                                            float* __restrict__ sigma) {
    __shared__ float fl[L_CHUNK * 32];
    __shared__ float vb[4][2][32];
    const int c    = blockIdx.x >> 2;
    const int tid  = threadIdx.x;
    const int wave = tid >> 6;
    const int lane = tid & 63;
    const int n    = lane & 31;
    const int pl   = lane >> 5;
    const int p    = ((blockIdx.x & 3) << 3) + (wave << 1) + pl;
    const int s0   = c * L_CHUNK;
    for (int i = tid; i < L_CHUNK * 32; i += 256) fl[i] = F[(size_t)s0 * 32 + i];
    __syncthreads();

    float et[32];
#pragma unroll
    for (int k = 0; k < 32; ++k) et[k] = __expf(trans[n * 32 + k]);

    float* vrow = &vb[wave][pl][0];
    float v  = __expf(trans[n * 32 + p] + fl[n]);
    float sg = 0.f;
    for (int s = 1; s < L_CHUNK; ++s) {
        vrow[n] = v;
        __builtin_amdgcn_s_waitcnt(0xC07F);   // lgkmcnt(0): wave-coherent LDS
        float a0 = 0.f, a1 = 0.f, a2 = 0.f, a3 = 0.f;
#pragma unroll
        for (int q = 0; q < 8; ++q) {
            const float4 wv = *(const float4*)&vrow[q * 4];
            a0 = __builtin_fmaf(et[q * 4 + 0], wv.x, a0);
            a1 = __builtin_fmaf(et[q * 4 + 1], wv.y, a1);
            a2 = __builtin_fmaf(et[q * 4 + 2], wv.z, a2);
            a3 = __builtin_fmaf(et[q * 4 + 3], wv.w, a3);
        }
        v = __expf(fl[s * 32 + n]) * ((a0 + a1) + (a2 + a3));
        if ((s & 7) == 7) {
            float m = v;
#pragma unroll
            for (int off = 16; off; off >>= 1) m = fmaxf(m, __shfl_xor(m, off, 32));
            if (m > 0.f) { v *= 1.0f / m; sg += __logf(m); }
        }
    }
    QT[(c * 32 + p) * 32 + n] = v;
    if (n == 0) sigma[c * 32 + p] = sg;
}

// ---------------- CRF pass B: parallel matrix fold (2 barriers/iter) -------
__global__ __launch_bounds__(1024) void crf_fold(const float* __restrict__ Qin,
                                                 const float* __restrict__ Sin,
                                                 const int fold, const int final,
                                                 float* __restrict__ Qout,
                                                 float* __restrict__ Sout,
                                                 const float* __restrict__ trans,
                                                 const float* __restrict__ F,
                                                 const int* __restrict__ lab,
                                                 float* __restrict__ out) {
    __shared__ float A[2][32][33];
    __shared__ float M[32][33];
    __shared__ float sgf[32];
    __shared__ float gred[16];
    __shared__ float gold_s;

    const int t = threadIdx.x;
    const int p = t >> 5, n = t & 31;
    const int c0 = blockIdx.x * fold;

    if (final) {
        float ga = 0.f;
        for (int s = t; s < S_LEN; s += 1024) {
            const int tg = lab[s];
            ga += F[(size_t)s * T_TAG + tg];
            const int tp = (s == 0) ? START_TAG : lab[s - 1];
            ga += trans[tg * T_TAG + tp];
        }
        if (t == 0) ga += trans[STOP_TAG * T_TAG + lab[S_LEN - 1]];
#pragma unroll
        for (int off = 32; off; off >>= 1) ga += __shfl_down(ga, off, 64);
        if ((t & 63) == 0) gred[t >> 6] = ga;
    }

    A[0][n][p] = Qin[(size_t)(c0 * 32 + p) * 32 + n];
    float sA = Sin[c0 * 32 + p];
    float mreg = Qin[(size_t)((c0 + 1) * 32 + p) * 32 + n];
    int cur = 0;

    for (int i = 1; i < fold; ++i) {
        const float sMn = Sin[(c0 + i) * 32 + n];
        float mmax = sMn;
#pragma unroll
        for (int off = 16; off; off >>= 1) mmax = fmaxf(mmax, __shfl_xor(mmax, off, 32));
        const float sMp = Sin[(c0 + i) * 32 + p];
        M[n][p] = mreg * __expf(sMp - mmax);
        if (i + 1 < fold) mreg = Qin[(size_t)((c0 + i + 1) * 32 + p) * 32 + n];
        __syncthreads();                         // M + A[cur] visible
        float acc = 0.f;
#pragma unroll 8
        for (int k = 0; k < 32; ++k)
            acc += M[n][k] * A[cur][k][p];
        float cm = acc;
#pragma unroll
        for (int off = 16; off; off >>= 1) cm = fmaxf(cm, __shfl_xor(cm, off, 32));
        cm = fmaxf(cm, 1e-37f);
        A[cur ^ 1][n][p] = acc / cm;
        sA = sA + mmax + __logf(cm);
        __syncthreads();                         // reads of M/A[cur] done
        cur ^= 1;
    }

    if (!final) {
        Qout[(size_t)(blockIdx.x * 32 + p) * 32 + n] = A[cur][n][p];
        if (n == 0) Sout[blockIdx.x * 32 + p] = sA;
        return;
    }

    if (n == 0) sgf[p] = sA;
    if (t == 0) {
        float s = 0.f;
#pragma unroll
        for (int i = 0; i < 16; ++i) s += gred[i];
        gold_s = s;
    }
    __syncthreads();
    if (t < 32) {
        float v = A[cur][t][START_TAG] * __expf(trans[STOP_TAG * T_TAG + t]);
#pragma unroll
        for (int off = 16; off; off >>= 1) v += __shfl_xor(v, off, 32);
        if (t == 0) out[0] = sgf[START_TAG] + __logf(v) - gold_s;
    }
}

// ---------------- launch ----------------
extern "C" void kernel_launch(void* const* d_in, const int* in_sizes, int n_in,
                              void* d_out, int out_size, void* d_ws, size_t ws_size,
                              hipStream_t stream) {
    const int*   ctx   = (const int*)d_in[0];
    const float* gz    = (const float*)d_in[1];
    const int*   lab   = (const int*)d_in[2];
    const float* emb   = (const float*)d_in[3];
    const float* w1    = (const float*)d_in[4];
    const float* b1    = (const float*)d_in[5];
    const float* w2    = (const float*)d_in[6];
    const float* b2    = (const float*)d_in[7];
    const float* trans = (const float*)d_in[8];
    float* out = (float*)d_out;

    char* ws = (char*)d_ws;
    bf16_t* Xb  = (bf16_t*)(ws + 0);               // 8192*3456*2 = 56,623,104
    bf16_t* W1b = (bf16_t*)(ws + 56623104);        // 1024*3456*2 =  7,077,888
    bf16_t* Hb  = (bf16_t*)(ws + 63700992);        // 8192*1024*2 = 16,777,216
    float*  F   = (float*)(ws + 80478208);         // 8192*32*4   =  1,048,576
    // overlays of the Xb region (Xb dead after gemm1; crfA/folds run after feats):
    float*  Q1  = (float*)(ws + 0);                // 16*32*32*4  =     65,536
    float*  S1  = (float*)(ws + 65536);            // 16*32*4     =      2,048
    float*  QT  = (float*)(ws + 1048576);          // 256*32*32*4 =  1,048,576
    float*  sg  = (float*)(ws + 2097152);          // 256*32*4    =     32,768

    build_all<<<S_LEN + H_DIM, 256, 0, stream>>>(ctx, gz, emb, w1, Xb, W1b);
    gemm1<<<dim3(S_LEN / 128, H_DIM / 128), 256, 0, stream>>>(Xb, W1b, b1, Hb);
    feats_mfma<<<S_LEN / 128, 256, 0, stream>>>(Hb, w2, b2, F);
    crfA<<<K_CHUNKS * 4, 256, 0, stream>>>(F, trans, QT, sg);
    crf_fold<<<16, 1024, 0, stream>>>(QT, sg, 16, 0, Q1, S1, trans, F, lab, out);
    crf_fold<<<1, 1024, 0, stream>>>(Q1, S1, 16, 1, nullptr, nullptr, trans, F, lab, out);
}